// Round 5
// baseline (416.962 us; speedup 1.0000x reference)
//
#include <hip/hip_runtime.h>
#include <hip/hip_bf16.h>

// Soft decision tree, fused MFMA implementation (f16, fp32 accum).
// BATCH=8192, D_IN=512, H1=128, H2=64, OUT=8, LEAVES=64, INTERNAL=63.
// R5: fully transposed dataflow — weights in MFMA A-slot, activations in
//     B-slot. Each wave owns 16 batch rows end-to-end; inter-stage layout
//     transforms are per-wave LDS round-trips (lgkmcnt only). ZERO
//     __syncthreads in the fused kernel. W1 streamed as A-frags 1:1 with
//     MFMA (ping-pong groups of 8). 64 KB LDS -> 2 blocks/CU.

typedef _Float16 f16;
typedef _Float16 f16x2 __attribute__((ext_vector_type(2)));
typedef _Float16 f16x8 __attribute__((ext_vector_type(8)));
typedef float    f32x4 __attribute__((ext_vector_type(4)));

#define MFMA16(a,b,c) __builtin_amdgcn_mfma_f32_16x16x32_f16((a),(b),(c),0,0,0)

// async global->LDS copy, 16 B/lane; dest = wave-uniform base + lane*16
typedef const __attribute__((address_space(1))) void gv_t;
typedef __attribute__((address_space(3))) void lv_t;
__device__ __forceinline__ void cp16(const void* g, char* lds_dst) {
  __builtin_amdgcn_global_load_lds((gv_t*)g, (lv_t*)lds_dst, 16, 0, 0);
}

// ---------------- workspace layout (bytes) ----------------
#define WS_XH    0u           // 8192*512 f16              = 8,388,608
#define WS_W1F   8388608u     // frags [(l*16+kc)*8+mt][64][8] = 8,388,608
#define WS_W2F   16777216u    // frags [l*16 + mt2*4+kc2][64][8] = 1,048,576
#define WS_W3F   17825792u    // frags [l*2 + kc3][64][8]  =   131,072
#define WS_RWF   17956864u    // frags [kc*4 + mt][64][8]  =    65,536
#define WS_RBP   18022400u    // rb padded to 64 f32       =       256
#define WS_NEED  18022656u

// ============ prep: convert x, fragment-pack W1/W2/W3/rW, pad rb ============
__global__ __launch_bounds__(256) void prep_all(
    const float* __restrict__ x, const float* __restrict__ rW,
    const float* __restrict__ rb, const float* __restrict__ W1,
    const float* __restrict__ W2, const float* __restrict__ W3,
    f16* __restrict__ xh, f16* __restrict__ w1f, f16* __restrict__ w2f,
    f16* __restrict__ w3f, f16* __restrict__ rwf, float* __restrict__ rbp) {
  __shared__ float sb[8704];
  const int bid = blockIdx.x, t = threadIdx.x;
  const int lane = t & 63, quad = (lane >> 4) & 3, l16 = lane & 15;

  if (bid < 64) {
    // ---- w1f: A-frags of W1^T. frag[(l*16+kc)*8+mt][lane][j] =
    //      W1[l][k=kc*32+quad*8+j][n1=mt*16+l16] ----
    const int l = bid;
#pragma unroll 1
    for (int kc = 0; kc < 16; ++kc) {
      const float* src = W1 + ((size_t)l * 512 + kc * 32) * 128;
#pragma unroll
      for (int i = 0; i < 4; ++i) {           // stage 32k x 128n fp32
        int f4 = i * 256 + t;
        int k = f4 >> 5, nf4 = f4 & 31;
        *(float4*)(sb + k * 132 + nf4 * 4) = *(const float4*)(src + k * 128 + nf4 * 4);
      }
      __syncthreads();
#pragma unroll
      for (int h = 0; h < 2; ++h) {
        int fid = h * 256 + t;
        int mt = fid >> 6, ln = fid & 63;
        int q = (ln >> 4) & 3, m = ln & 15;
        f16x8 o;
#pragma unroll
        for (int j = 0; j < 8; ++j) o[j] = (f16)sb[(q * 8 + j) * 132 + mt * 16 + m];
        *(f16x8*)(w1f + ((size_t)((l * 16 + kc) * 8 + mt)) * 512 + ln * 8) = o;
      }
      __syncthreads();
    }
  } else if (bid < 128) {
    // ---- w2f + w3f (one leaf per block) ----
    const int l = bid - 64;
    const float* src = W2 + (size_t)l * 128 * 64;
#pragma unroll
    for (int i = 0; i < 8; ++i) {             // stage 128k x 64n fp32
      int f4 = i * 256 + t;
      int k = f4 >> 4, nf4 = f4 & 15;
      *(float4*)(sb + k * 68 + nf4 * 4) = *(const float4*)(src + k * 64 + nf4 * 4);
    }
    __syncthreads();
#pragma unroll
    for (int i = 0; i < 4; ++i) {
      int fid = i * 256 + t;                  // fr = mt2*4+kc2
      int fr = fid >> 6, ln = fid & 63;
      int mt2 = fr >> 2, kc2 = fr & 3;
      int q = (ln >> 4) & 3, m = ln & 15;
      f16x8 o;
#pragma unroll
      for (int j = 0; j < 8; ++j) o[j] = (f16)sb[(kc2 * 32 + q * 8 + j) * 68 + mt2 * 16 + m];
      *(f16x8*)(w2f + ((size_t)(l * 16 + fr)) * 512 + ln * 8) = o;
    }
    if (t < 128) {                            // w3f (o padded 8->16 w/ zeros)
      int kc3 = t >> 6, ln = t & 63;
      int q = (ln >> 4) & 3, m = ln & 15;
      f16x8 o;
#pragma unroll
      for (int j = 0; j < 8; ++j)
        o[j] = (m < 8) ? (f16)W3[((size_t)l * 64 + kc3 * 32 + q * 8 + j) * 8 + m] : (f16)0.f;
      *(f16x8*)(w3f + ((size_t)(l * 2 + kc3)) * 512 + ln * 8) = o;
    }
  } else if (bid < 384) {
    // ---- xh: fp32 -> f16 ----
    size_t base = (size_t)(bid - 128) * 16384;
#pragma unroll
    for (int i = 0; i < 8; ++i) {
      size_t idx = base + ((size_t)t + i * 256) * 8;
      float4 a = *(const float4*)(x + idx);
      float4 b = *(const float4*)(x + idx + 4);
      f16x8 h = {(f16)a.x,(f16)a.y,(f16)a.z,(f16)a.w,(f16)b.x,(f16)b.y,(f16)b.z,(f16)b.w};
      *(f16x8*)(xh + idx) = h;
    }
  } else {
    // ---- rwf A-frags + rbp ----
    int rel = bid - 384;                      // 0..3
#pragma unroll
    for (int i = 0; i < 4; ++i) {
      int fid = rel * 16 + (t >> 6) * 4 + i;  // fid = kc*4+mt
      int kc = fid >> 2, mt = fid & 3;
      f16x8 o;
#pragma unroll
      for (int j = 0; j < 8; ++j) {
        int node = mt * 16 + l16;
        o[j] = (node < 63) ? (f16)rW[(size_t)node * 512 + kc * 32 + quad * 8 + j] : (f16)0.f;
      }
      *(f16x8*)(rwf + ((size_t)fid) * 512 + lane * 8) = o;
    }
    if (rel == 3 && t < 64) rbp[t] = (t < 63) ? rb[t] : 0.f;
  }
}

// ============ fused: router + per-leaf MLP + weighted sum (ZERO barriers) ====
// 256 threads (4 waves), each wave owns 16 batch rows. Grid 512 XCD-swizzled.
__global__ __launch_bounds__(256, 2) void fused_tree(
    const f16* __restrict__ xh, const f16* __restrict__ w1f,
    const f16* __restrict__ w2f, const f16* __restrict__ w3f,
    const f16* __restrict__ rwf, const float* __restrict__ rbp,
    const float* __restrict__ b1, const float* __restrict__ b2,
    const float* __restrict__ b3, float* __restrict__ out) {
  __shared__ char smem[65536];               // 4 waves x 16 KB private
  const int t = threadIdx.x;
  const int w = t >> 6, L = t & 63;
  const int quad = L >> 4, l16 = L & 15;

  // XCD-aware decode: 2 XCDs per leaf-group (W1 slice L2-resident)
  const int bid = blockIdx.x;
  const int r8 = bid & 7;
  const int lg0 = (r8 >> 1) * 16;
  const int b0 = ((bid >> 3) * 2 + (r8 & 1)) * 64;
  const int bw = b0 + w * 16;                // this wave's 16 batch rows

  char* myws = smem + w * 16384;

  // ---- stage x rows bw..bw+15 (unit-swizzled), then B-frags to regs ----
#pragma unroll
  for (int r = 0; r < 16; ++r)
    cp16(xh + ((size_t)(bw + r)) * 512 + (size_t)((L ^ (r & 7))) * 8, myws + r * 1024);
  __asm__ volatile("s_waitcnt vmcnt(0)" ::: "memory");

  f16x8 xb[16];
#pragma unroll
  for (int kc = 0; kc < 16; ++kc) {
    int u = (kc * 4 + quad) ^ (l16 & 7);
    xb[kc] = *(const f16x8*)(myws + l16 * 1024 + u * 16);
  }

  // ---- router: route^T = rW^T-frags (A) x X-frags (B); per-wave LDS, no barrier
  {
    const f16* rwl = rwf + (size_t)L * 8;
    f16x8 rbuf[2][4];
#pragma unroll
    for (int mt = 0; mt < 4; ++mt) rbuf[0][mt] = *(const f16x8*)(rwl + (size_t)mt * 512);
    f32x4 accr[4];
#pragma unroll
    for (int mt = 0; mt < 4; ++mt) accr[mt] = (f32x4){0.f,0.f,0.f,0.f};
#pragma unroll
    for (int kc = 0; kc < 16; ++kc) {
      if (kc < 15) {
#pragma unroll
        for (int mt = 0; mt < 4; ++mt)
          rbuf[(kc + 1) & 1][mt] = *(const f16x8*)(rwl + (size_t)((kc + 1) * 4 + mt) * 512);
      }
#pragma unroll
      for (int mt = 0; mt < 4; ++mt)
        accr[mt] = MFMA16(rbuf[kc & 1][mt], xb[kc], accr[mt]);
    }
    float* rws = (float*)myws;               // route_ws [64 node][17] (x dead)
#pragma unroll
    for (int mt = 0; mt < 4; ++mt) {
      f32x4 rbv = *(const f32x4*)(rbp + mt * 16 + quad * 4);
#pragma unroll
      for (int rg = 0; rg < 4; ++rg) {
        int node = mt * 16 + quad * 4 + rg;
        rws[node * 17 + l16] = 1.f / (1.f + __expf(-(accr[mt][rg] + rbv[rg])));
      }
    }
  }
  // ---- path products for 16 leaves (per-wave LDS reads, lgkmcnt only) ----
  float p_lane[16];
  {
    const float* rws = (const float*)myws;
#pragma unroll
    for (int j = 0; j < 16; ++j) {
      int l = lg0 + j;
      float pr = 1.f;
#pragma unroll
      for (int lev = 0; lev < 6; ++lev) {
        int node = (1 << lev) - 1 + (l >> (6 - lev));
        float d = rws[node * 17 + l16];
        pr *= ((l >> (5 - lev)) & 1) ? (1.f - d) : d;
      }
      p_lane[j] = pr;
    }
  }

  f16* h1ws = (f16*)myws;                    // [16][136] f16 (route_ws dead)
  f16* h2ws = (f16*)(myws + 8192);           // [16][72]  f16

  // ---- main leaf loop: W1 A-frag stream, 1:1 load:mfma, ping-pong ----
  const f16* w1lane = w1f + (size_t)lg0 * 65536 + (size_t)L * 8;
  f16x8 wbuf[2][8];
#pragma unroll
  for (int mt = 0; mt < 8; ++mt) wbuf[0][mt] = *(const f16x8*)(w1lane + (size_t)mt * 512);

  f32x4 acc3 = {0.f,0.f,0.f,0.f};

#pragma unroll 1
  for (int li = 0; li < 16; ++li) {
    const int l = lg0 + li;

    // ---- GEMM1: H1^T = W1^T-frags x X-frags ----
    f32x4 acc1[8];
#pragma unroll
    for (int mt = 0; mt < 8; ++mt) acc1[mt] = (f32x4){0.f,0.f,0.f,0.f};
#pragma unroll
    for (int kc = 0; kc < 16; ++kc) {
      int nidx = li * 16 + kc + 1;
      if (nidx > 255) nidx = 255;
#pragma unroll
      for (int mt = 0; mt < 8; ++mt)
        wbuf[(kc + 1) & 1][mt] = *(const f16x8*)(w1lane + (size_t)nidx * 4096 + (size_t)mt * 512);
#pragma unroll
      for (int mt = 0; mt < 8; ++mt)
        acc1[mt] = MFMA16(wbuf[kc & 1][mt], xb[kc], acc1[mt]);
    }

    // stage-2/3 operand loads (latency overlapped by epilogue1)
    f16x8 w2frag[16];
#pragma unroll
    for (int fr = 0; fr < 16; ++fr)
      w2frag[fr] = *(const f16x8*)(w2f + (size_t)(l * 16 + fr) * 512 + (size_t)L * 8);
    f16x8 w3frag[2];
#pragma unroll
    for (int kc3 = 0; kc3 < 2; ++kc3)
      w3frag[kc3] = *(const f16x8*)(w3f + (size_t)(l * 2 + kc3) * 512 + (size_t)L * 8);
    f32x4 b2v[4];
#pragma unroll
    for (int mt2 = 0; mt2 < 4; ++mt2)
      b2v[mt2] = *(const f32x4*)(b2 + l * 64 + mt2 * 16 + quad * 4);

    // ---- epilogue1: +b1, relu -> h1ws[b][n1] (wave-private) ----
#pragma unroll
    for (int mt = 0; mt < 8; ++mt) {
      f32x4 b1v = *(const f32x4*)(b1 + l * 128 + mt * 16 + quad * 4);
      float v0 = acc1[mt][0] + b1v[0]; v0 = v0 > 0.f ? v0 : 0.f;
      float v1 = acc1[mt][1] + b1v[1]; v1 = v1 > 0.f ? v1 : 0.f;
      float v2 = acc1[mt][2] + b1v[2]; v2 = v2 > 0.f ? v2 : 0.f;
      float v3 = acc1[mt][3] + b1v[3]; v3 = v3 > 0.f ? v3 : 0.f;
      f16* dst = h1ws + l16 * 136 + mt * 16 + quad * 4;
      *(f16x2*)(dst)     = (f16x2){(f16)v0, (f16)v1};
      *(f16x2*)(dst + 2) = (f16x2){(f16)v2, (f16)v3};
    }

    // ---- GEMM2: H2^T = W2^T-frags x H1'^T-frags (LDS round-trip) ----
    f16x8 bf2[4];
#pragma unroll
    for (int kc2 = 0; kc2 < 4; ++kc2)
      bf2[kc2] = *(const f16x8*)(h1ws + l16 * 136 + kc2 * 32 + quad * 8);
    f32x4 acc2[4];
#pragma unroll
    for (int mt2 = 0; mt2 < 4; ++mt2) acc2[mt2] = (f32x4){0.f,0.f,0.f,0.f};
#pragma unroll
    for (int mt2 = 0; mt2 < 4; ++mt2)
#pragma unroll
      for (int kc2 = 0; kc2 < 4; ++kc2)
        acc2[mt2] = MFMA16(w2frag[mt2 * 4 + kc2], bf2[kc2], acc2[mt2]);

    // ---- epilogue2: +b2, relu, x p -> h2ws[b][n2] ----
    const float pv = p_lane[li];
#pragma unroll
    for (int mt2 = 0; mt2 < 4; ++mt2) {
      float v0 = acc2[mt2][0] + b2v[mt2][0]; v0 = (v0 > 0.f ? v0 : 0.f) * pv;
      float v1 = acc2[mt2][1] + b2v[mt2][1]; v1 = (v1 > 0.f ? v1 : 0.f) * pv;
      float v2 = acc2[mt2][2] + b2v[mt2][2]; v2 = (v2 > 0.f ? v2 : 0.f) * pv;
      float v3 = acc2[mt2][3] + b2v[mt2][3]; v3 = (v3 > 0.f ? v3 : 0.f) * pv;
      f16* dst = h2ws + l16 * 72 + mt2 * 16 + quad * 4;
      *(f16x2*)(dst)     = (f16x2){(f16)v0, (f16)v1};
      *(f16x2*)(dst + 2) = (f16x2){(f16)v2, (f16)v3};
    }

    // ---- GEMM3: out^T += W3^T-frags x H2''^T-frags ----
    f16x8 bf3[2];
#pragma unroll
    for (int kc3 = 0; kc3 < 2; ++kc3)
      bf3[kc3] = *(const f16x8*)(h2ws + l16 * 72 + kc3 * 32 + quad * 8);
#pragma unroll
    for (int kc3 = 0; kc3 < 2; ++kc3)
      acc3 = MFMA16(w3frag[kc3], bf3[kc3], acc3);
  }

  // ---- final: + sum_li p*b3, atomicAdd (quads 0,1 hold real o<8) ----
  if (quad < 2) {
    float vo[4] = {acc3[0], acc3[1], acc3[2], acc3[3]};
#pragma unroll
    for (int li = 0; li < 16; ++li) {
      f32x4 b3v = *(const f32x4*)(b3 + (lg0 + li) * 8 + quad * 4);
#pragma unroll
      for (int rg = 0; rg < 4; ++rg) vo[rg] += p_lane[li] * b3v[rg];
    }
#pragma unroll
    for (int rg = 0; rg < 4; ++rg)
      atomicAdd(out + (size_t)(bw + l16) * 8 + quad * 4 + rg, vo[rg]);
  }
}

extern "C" void kernel_launch(void* const* d_in, const int* in_sizes, int n_in,
                              void* d_out, int out_size, void* d_ws, size_t ws_size,
                              hipStream_t stream) {
  const float* x  = (const float*)d_in[0];
  const float* rW = (const float*)d_in[1];
  const float* rb = (const float*)d_in[2];
  const float* W1 = (const float*)d_in[3];
  const float* b1 = (const float*)d_in[4];
  const float* W2 = (const float*)d_in[5];
  const float* b2 = (const float*)d_in[6];
  const float* W3 = (const float*)d_in[7];
  const float* b3 = (const float*)d_in[8];
  float* out = (float*)d_out;

  if (ws_size < WS_NEED) return;

  char* ws = (char*)d_ws;
  f16*   xh  = (f16*)(ws + WS_XH);
  f16*   w1f = (f16*)(ws + WS_W1F);
  f16*   w2f = (f16*)(ws + WS_W2F);
  f16*   w3f = (f16*)(ws + WS_W3F);
  f16*   rwf = (f16*)(ws + WS_RWF);
  float* rbp = (float*)(ws + WS_RBP);

  hipMemsetAsync(d_out, 0, (size_t)out_size * sizeof(float), stream);
  prep_all<<<388, 256, 0, stream>>>(x, rW, rb, W1, W2, W3, xh, w1f, w2f, w3f, rwf, rbp);
  fused_tree<<<512, 256, 0, stream>>>(xh, w1f, w2f, w3f, rwf, rbp, b1, b2, b3, out);
}

// Round 7
// 243.671 us; speedup vs baseline: 1.7112x; 1.7112x over previous
//
#include <hip/hip_runtime.h>
#include <hip/hip_bf16.h>

// Soft decision tree, fused MFMA implementation (f16, fp32 accum).
// BATCH=8192, D_IN=512, H1=128, H2=64, OUT=8, LEAVES=64, INTERNAL=63.
// R7 = R6 with the W1 prefetch leaf-stride bug fixed:
//     w1f layout is [l][ng][kq] (leaf stride 65536 halfs, 32-frag wave slice
//     contiguous 16384 halfs). R6 advanced the stream by cc*2048 (leaf stride
//     16384) -> wrong leaf weights for li>0. Now: addr = (g>>3)*65536 +
//     (g&7)*2048, g = li*8 + q + 2 (depth-2 ring of 4-frag chunks).
//  - 2 barriers/leaf; GEMM3 via wave-private h2 (no barrier, R5-validated)
//  - prep spread over 1360 blocks, conflict-free staging

typedef _Float16 f16;
typedef _Float16 f16x8 __attribute__((ext_vector_type(8)));
typedef float    f32x4 __attribute__((ext_vector_type(4)));
typedef float    f32x16 __attribute__((ext_vector_type(16)));

#define MFMA16(a,b,c) __builtin_amdgcn_mfma_f32_16x16x32_f16((a),(b),(c),0,0,0)
#define MFMA32(a,b,c) __builtin_amdgcn_mfma_f32_32x32x16_f16((a),(b),(c),0,0,0)

typedef const __attribute__((address_space(1))) void gv_t;
typedef __attribute__((address_space(3))) void lv_t;
__device__ __forceinline__ void cp16(const void* g, char* lds_dst) {
  __builtin_amdgcn_global_load_lds((gv_t*)g, (lv_t*)lds_dst, 16, 0, 0);
}

// ---------------- workspace layout (bytes) ----------------
#define WS_XH    0u           // 8192*512 f16                = 8,388,608
#define WS_W1F   8388608u     // mfma32 B-frags [l][ng][kq][64][8] = 8,388,608
#define WS_W2F   16777216u    // mfma16 B-frags [(l*4+nb)*4+ks][64][8]  = 1,048,576
#define WS_W3F   17825792u    // mfma16 B-frags [l*2+kc3][64][8]        =   131,072
#define WS_RWF   17956864u    // mfma32 B-frags [ngr*32+ks][64][8]      =    65,536
#define WS_NEED  18022400u

// ---------------- fused-kernel LDS (static, 62 KB) ----------------
#define L_X   0        // x rows 32..63 [32][512] f16 swizzled = 32768
#define L_H1  32768    // h1 [64][136] f16 = 17408 ; route_s overlay [64][68] f32
#define L_H2  50176    // h2 wave-private [4][16][72] f16 = 9216
#define L_P   59392    // p [64][16] f32 = 4096
#define L_TOT 63488    // 2 blocks/CU

// ============ prep: convert x + fragment-pack all weights ============
__global__ __launch_bounds__(256) void prep_all(
    const float* __restrict__ x, const float* __restrict__ rW,
    const float* __restrict__ W1, const float* __restrict__ W2,
    const float* __restrict__ W3,
    f16* __restrict__ xh, f16* __restrict__ w1f, f16* __restrict__ w2f,
    f16* __restrict__ w3f, f16* __restrict__ rwf) {
  __shared__ float sb[8704];
  const int bid = blockIdx.x, t = threadIdx.x;
  const int lane = t & 63, quad = (lane >> 4) & 3, l16 = lane & 15;
  const int r31 = lane & 31, kp = lane >> 5;

  if (bid < 1024) {
    // ---- w1f: one (leaf, 32k-chunk) tile per block ----
    const int l = bid >> 4, kc32 = bid & 15;
    const float* src = W1 + ((size_t)l * 512 + kc32 * 32) * 128;
#pragma unroll
    for (int i = 0; i < 4; ++i) {            // stage 32k x 128n fp32, stride 132
      int f4 = i * 256 + t;
      int k = f4 >> 5, nf4 = f4 & 31;
      *(float4*)(sb + k * 132 + nf4 * 4) = *(const float4*)(src + k * 128 + nf4 * 4);
    }
    __syncthreads();
#pragma unroll
    for (int h = 0; h < 2; ++h) {
      int fid = (t >> 6) + h * 4;            // 0..7 = ng*2 + hh
      int ng = fid >> 1, hh = fid & 1;
      f16x8 o;
#pragma unroll
      for (int j = 0; j < 8; ++j) o[j] = (f16)sb[(hh * 16 + kp * 8 + j) * 132 + ng * 32 + r31];
      *(f16x8*)(w1f + ((size_t)(l * 4 + ng) * 32 + kc32 * 2 + hh) * 512 + lane * 8) = o;
    }
  } else if (bid < 1280) {
    // ---- xh: fp32 -> f16 ----
    size_t base = (size_t)(bid - 1024) * 16384;
#pragma unroll
    for (int i = 0; i < 8; ++i) {
      size_t idx = base + ((size_t)t + i * 256) * 8;
      float4 a = *(const float4*)(x + idx);
      float4 b = *(const float4*)(x + idx + 4);
      f16x8 h = {(f16)a.x,(f16)a.y,(f16)a.z,(f16)a.w,(f16)b.x,(f16)b.y,(f16)b.z,(f16)b.w};
      *(f16x8*)(xh + idx) = h;
    }
  } else if (bid < 1344) {
    // ---- w2f + w3f (one leaf per block) ----
    const int l = bid - 1280;
    const float* src = W2 + (size_t)l * 128 * 64;
#pragma unroll
    for (int i = 0; i < 8; ++i) {            // stage 128k x 64n fp32, stride 68
      int f4 = i * 256 + t;
      int k = f4 >> 4, nf4 = f4 & 15;
      *(float4*)(sb + k * 68 + nf4 * 4) = *(const float4*)(src + k * 64 + nf4 * 4);
    }
    __syncthreads();
#pragma unroll
    for (int i = 0; i < 4; ++i) {
      int fid = (t >> 6) + i * 4;            // 0..15 = nb*4 + ks
      int nb = fid >> 2, ks = fid & 3;
      f16x8 o;
#pragma unroll
      for (int j = 0; j < 8; ++j) o[j] = (f16)sb[(ks * 32 + quad * 8 + j) * 68 + nb * 16 + l16];
      *(f16x8*)(w2f + ((size_t)(l * 4 + nb) * 4 + ks) * 512 + lane * 8) = o;
    }
    if (t < 128) {                           // w3f (o padded 8->16 zero)
      int kc3 = t >> 6;
      f16x8 o;
#pragma unroll
      for (int j = 0; j < 8; ++j)
        o[j] = (l16 < 8) ? (f16)W3[((size_t)l * 64 + kc3 * 32 + quad * 8 + j) * 8 + l16] : (f16)0.f;
      *(f16x8*)(w3f + ((size_t)(l * 2 + kc3)) * 512 + lane * 8) = o;
    }
  } else {
    // ---- rwf: router-W mfma32 B-frags (node 63 zero) ----
    int c = (bid - 1344) * 4 + (t >> 6);     // 0..63 = ngr*32 + ks
    int n = ((c >> 5) * 32) + r31;
    int k0 = (c & 31) * 16 + kp * 8;
    f16x8 o;
#pragma unroll
    for (int j = 0; j < 8; ++j)
      o[j] = (n < 63) ? (f16)rW[(size_t)n * 512 + k0 + j] : (f16)0.f;
    *(f16x8*)(rwf + (size_t)c * 512 + lane * 8) = o;
  }
}

// ============ fused: router + per-leaf MLP + weighted sum ============
// 256 threads (4 waves). Block: 64 batch rows x 16 leaves. Grid 512.
__global__ __launch_bounds__(256, 2) void fused_tree(
    const f16* __restrict__ xh, const f16* __restrict__ w1f,
    const f16* __restrict__ w2f, const f16* __restrict__ w3f,
    const f16* __restrict__ rwf, const float* __restrict__ rb,
    const float* __restrict__ b1, const float* __restrict__ b2,
    const float* __restrict__ b3, float* __restrict__ out) {
  __shared__ char smem[L_TOT];
  f16*   x_lds   = (f16*)(smem + L_X);
  f16*   h1_lds  = (f16*)(smem + L_H1);
  float* route_s = (float*)(smem + L_H1);   // overlay, dead before h1 use
  float* p_lds   = (float*)(smem + L_P);

  const int t = threadIdx.x;
  const int w = t >> 6, L = t & 63;
  const int l16 = L & 15, quad = L >> 4;
  const int r31 = L & 31, kp = L >> 5;

  // XCD-aware decode: 2 XCDs per leaf-group (W1 slice L2-resident)
  const int bid = blockIdx.x;
  const int r8 = bid & 7;
  const int lg0 = (r8 >> 1) * 16;
  const int b0 = ((bid >> 3) * 2 + (r8 & 1)) * 64;

  f16* h2w = (f16*)(smem + L_H2 + w * 2304); // wave-private [16][72]

  // ---- stage x rows b0+32..63 into swizzled LDS ----
#pragma unroll
  for (int j = 0; j < 8; ++j) {
    int r = w * 8 + j;
    int u = (L & 56) | ((L & 7) ^ (r & 7));
    cp16(xh + (size_t)(b0 + 32 + r) * 512 + u * 8, smem + r * 1024);
  }
  // ---- a0: rows b0..b0+31 in registers, mfma32 A-layout ----
  f16x8 a0[32];
#pragma unroll
  for (int ks = 0; ks < 32; ++ks)
    a0[ks] = *(const f16x8*)(xh + (size_t)(b0 + r31) * 512 + ks * 16 + kp * 8);
  __syncthreads();

  // ---- router: waves 0,1 -> rows 0-31 (reg A), waves 2,3 -> rows 32-63 ----
  {
    const int btr = w >> 1, ngr = w & 1;
    f32x16 accr;
#pragma unroll
    for (int i = 0; i < 16; ++i) accr[i] = 0.f;
    const f16* rbase = rwf + (size_t)(ngr * 32) * 512 + (size_t)L * 8;
#pragma unroll
    for (int ks = 0; ks < 32; ++ks) {
      f16x8 B = *(const f16x8*)(rbase + (size_t)ks * 512);
      f16x8 A;
      if (btr == 0) A = a0[ks];
      else {
        int u = ks * 2 + kp;
        A = *(const f16x8*)(x_lds + r31 * 512 + ((u & 56) | ((u & 7) ^ (r31 & 7))) * 8);
      }
      accr = MFMA32(A, B, accr);
    }
    int node = ngr * 32 + r31;
    float rbv = (node < 63) ? rb[node] : 0.f;
#pragma unroll
    for (int reg = 0; reg < 16; ++reg) {
      int rr = btr * 32 + (reg & 3) + 8 * (reg >> 2) + 4 * kp;
      route_s[rr * 68 + node] = 1.f / (1.f + __expf(-(accr[reg] + rbv)));
    }
  }
  __syncthreads();
  // ---- path products ----
  float prod[4];
  {
    int row = t >> 2, j0 = t & 3;
#pragma unroll
    for (int i = 0; i < 4; ++i) {
      int l = lg0 + j0 * 4 + i;
      float pr = 1.f;
#pragma unroll
      for (int lev = 0; lev < 6; ++lev) {
        int node = (1 << lev) - 1 + (l >> (6 - lev));
        float d = route_s[row * 68 + node];
        pr *= ((l >> (5 - lev)) & 1) ? (1.f - d) : d;
      }
      prod[i] = pr;
    }
  }
  __syncthreads();
  {
    int row = t >> 2, j0 = t & 3;
#pragma unroll
    for (int i = 0; i < 4; ++i) p_lds[row * 16 + j0 * 4 + i] = prod[i];
  }

  // ---- GEMM1 W1 stream preamble: chunks g=0,1 (leaf 0) into ring slots 0,1 ----
  const f16* w1base = w1f + (size_t)(lg0 * 4 + w) * 32 * 512 + (size_t)L * 8;
  f16x8 bq[4][4];
#pragma unroll
  for (int s = 0; s < 4; ++s) {
    bq[0][s] = *(const f16x8*)(w1base + (size_t)s * 512);
    bq[1][s] = *(const f16x8*)(w1base + 2048 + (size_t)s * 512);
  }
  f32x4 acc3 = {0.f, 0.f, 0.f, 0.f};
  const int n1 = w * 32 + r31;
  __syncthreads();   // p visible; route_s dead -> h1 writable

#pragma unroll 1
  for (int li = 0; li < 16; ++li) {
    const int l = lg0 + li;

    // ---- GEMM1: X(64x512) @ W1[l] -> H1(64x128); depth-2 pipelined stream ----
    f32x16 acc1r, acc1l;
#pragma unroll
    for (int i = 0; i < 16; ++i) { acc1r[i] = 0.f; acc1l[i] = 0.f; }
#pragma unroll
    for (int q = 0; q < 8; ++q) {
      // prefetch chunk g (2 ahead). w1f leaf stride = 65536 halfs (BUGFIX:
      // R6 used g*2048 which strides leaves at 16384 -> wrong weights)
      int g = li * 8 + q + 2;
      if (g > 127) g = 127;
      const f16* pre = w1base + ((size_t)(g >> 3) << 16) + (size_t)(g & 7) * 2048;
#pragma unroll
      for (int s = 0; s < 4; ++s)
        bq[(q + 2) & 3][s] = *(const f16x8*)(pre + (size_t)s * 512);
#pragma unroll
      for (int s = 0; s < 4; ++s) {
        int ks = q * 4 + s;
        int u = ks * 2 + kp;
        f16x8 A1 = *(const f16x8*)(x_lds + r31 * 512 + ((u & 56) | ((u & 7) ^ (r31 & 7))) * 8);
        acc1r = MFMA32(a0[ks], bq[q & 3][s], acc1r);
        acc1l = MFMA32(A1, bq[q & 3][s], acc1l);
      }
    }

    // ---- epilogue1: +b1, relu -> h1 (both halves) ----
    {
      float bias1 = b1[l * 128 + n1];
#pragma unroll
      for (int reg = 0; reg < 16; ++reg) {
        int rr = (reg & 3) + 8 * (reg >> 2) + 4 * kp;
        float vr = acc1r[reg] + bias1;
        float vl = acc1l[reg] + bias1;
        h1_lds[rr * 136 + n1]        = (f16)(vr > 0.f ? vr : 0.f);
        h1_lds[(32 + rr) * 136 + n1] = (f16)(vl > 0.f ? vl : 0.f);
      }
    }
    // prefetch GEMM2/3 B-frags + biases (latency hidden by barrier)
    f16x8 bw2[4][4];
#pragma unroll
    for (int nb = 0; nb < 4; ++nb)
#pragma unroll
      for (int ks = 0; ks < 4; ++ks)
        bw2[nb][ks] = *(const f16x8*)(w2f + ((size_t)(l * 4 + nb) * 4 + ks) * 512 + (size_t)L * 8);
    f16x8 bw3[2];
#pragma unroll
    for (int kc3 = 0; kc3 < 2; ++kc3)
      bw3[kc3] = *(const f16x8*)(w3f + ((size_t)(l * 2 + kc3)) * 512 + (size_t)L * 8);
    __syncthreads();   // bar1: h1 visible

    // ---- GEMM2: rows w*16..+15, all 64 n2 (per-wave) ----
    f16x8 afr[4];
#pragma unroll
    for (int ks = 0; ks < 4; ++ks)
      afr[ks] = *(const f16x8*)(h1_lds + (w * 16 + l16) * 136 + ks * 32 + quad * 8);
    __syncthreads();   // bar2: all h1 reads done -> next-leaf h1 writable

    f32x4 acc2[4];
#pragma unroll
    for (int nb = 0; nb < 4; ++nb) acc2[nb] = (f32x4){0.f,0.f,0.f,0.f};
#pragma unroll
    for (int ks = 0; ks < 4; ++ks)
#pragma unroll
      for (int nb = 0; nb < 4; ++nb)
        acc2[nb] = MFMA16(afr[ks], bw2[nb][ks], acc2[nb]);

    // ---- epilogue2: +b2, relu, x p -> wave-private h2 ----
    float pv[4];
#pragma unroll
    for (int rg = 0; rg < 4; ++rg)
      pv[rg] = p_lds[(w * 16 + quad * 4 + rg) * 16 + li];
#pragma unroll
    for (int nb = 0; nb < 4; ++nb) {
      int n2 = nb * 16 + l16;
      float bias2 = b2[l * 64 + n2];
#pragma unroll
      for (int rg = 0; rg < 4; ++rg) {
        float v = acc2[nb][rg] + bias2;
        v = v > 0.f ? v : 0.f;
        h2w[(quad * 4 + rg) * 72 + n2] = (f16)(v * pv[rg]);
      }
    }

    // ---- GEMM3 (wave-private, no barrier) ----
#pragma unroll
    for (int kc3 = 0; kc3 < 2; ++kc3) {
      f16x8 A3 = *(const f16x8*)(h2w + l16 * 72 + kc3 * 32 + quad * 8);
      acc3 = MFMA16(A3, bw3[kc3], acc3);
    }
  }

  // ---- final: + sum_li p*b3, atomicAdd ----
  if (l16 < 8) {
    float b3v[16];
#pragma unroll
    for (int li2 = 0; li2 < 16; ++li2) b3v[li2] = b3[(lg0 + li2) * 8 + l16];
#pragma unroll
    for (int rg = 0; rg < 4; ++rg) {
      int rloc = w * 16 + quad * 4 + rg;
      float v = acc3[rg];
#pragma unroll
      for (int li2 = 0; li2 < 16; ++li2) v += p_lds[rloc * 16 + li2] * b3v[li2];
      atomicAdd(out + (size_t)(b0 + rloc) * 8 + l16, v);
    }
  }
}

extern "C" void kernel_launch(void* const* d_in, const int* in_sizes, int n_in,
                              void* d_out, int out_size, void* d_ws, size_t ws_size,
                              hipStream_t stream) {
  const float* x  = (const float*)d_in[0];
  const float* rW = (const float*)d_in[1];
  const float* rb = (const float*)d_in[2];
  const float* W1 = (const float*)d_in[3];
  const float* b1 = (const float*)d_in[4];
  const float* W2 = (const float*)d_in[5];
  const float* b2 = (const float*)d_in[6];
  const float* W3 = (const float*)d_in[7];
  const float* b3 = (const float*)d_in[8];
  float* out = (float*)d_out;

  if (ws_size < WS_NEED) return;

  char* ws = (char*)d_ws;
  f16* xh  = (f16*)(ws + WS_XH);
  f16* w1f = (f16*)(ws + WS_W1F);
  f16* w2f = (f16*)(ws + WS_W2F);
  f16* w3f = (f16*)(ws + WS_W3F);
  f16* rwf = (f16*)(ws + WS_RWF);

  hipMemsetAsync(d_out, 0, (size_t)out_size * sizeof(float), stream);
  prep_all<<<1360, 256, 0, stream>>>(x, rW, W1, W2, W3, xh, w1f, w2f, w3f, rwf);
  fused_tree<<<512, 256, 0, stream>>>(xh, w1f, w2f, w3f, rwf, rb, b1, b2, b3, out);
}

// Round 8
// 198.103 us; speedup vs baseline: 2.1048x; 1.2300x over previous
//
#include <hip/hip_runtime.h>
#include <hip/hip_bf16.h>

// Soft decision tree, fused MFMA implementation (f16 inputs, fp32 accum).
// BATCH=8192, D_IN=512, H1=128, H2=64, OUT=8, LEAVES=64, INTERNAL=63.
// R8 = R4 (125 us verified) with ONE change: GEMM1 inner loop batches the 4
//     A1 ds_read_b128 at the top of each q-iteration (was: per-s dependent
//     ds_read -> mfma chain), then global prefetch, then 4 reg-only acc1r
//     MFMAs (hide lgkmcnt), then 4 acc1l MFMAs. Everything else identical.

typedef _Float16 f16;
typedef _Float16 f16x8 __attribute__((ext_vector_type(8)));
typedef float    f32x4 __attribute__((ext_vector_type(4)));
typedef float    f32x16 __attribute__((ext_vector_type(16)));

#define MFMA16(a,b,c) __builtin_amdgcn_mfma_f32_16x16x32_f16((a),(b),(c),0,0,0)
#define MFMA32(a,b,c) __builtin_amdgcn_mfma_f32_32x32x16_f16((a),(b),(c),0,0,0)

// async global->LDS copy, 16 B per lane; dest = wave-uniform base + lane*16
typedef const __attribute__((address_space(1))) void gv_t;
typedef __attribute__((address_space(3))) void lv_t;
__device__ __forceinline__ void cp16(const void* g, char* lds_dst) {
  __builtin_amdgcn_global_load_lds((gv_t*)g, (lv_t*)lds_dst, 16, 0, 0);
}

// ---------------- workspace layout (bytes) ----------------
#define WS_XH    0u           // 8192*512 f16           = 8,388,608
#define WS_W1F   8388608u     // 64l*4ng*32ks*64*8 f16  = 8,388,608
#define WS_W2F   16777216u    // 64l*4nb*4ks*64*8 f16   = 1,048,576
#define WS_W3F   17825792u    // 64l*2ks*64*8 f16       =   131,072
#define WS_RWF   17956864u    // 2ng*32ks*64*8 f16      =    65,536
#define WS_NEED  18022400u

// ---------------- fused-kernel LDS (static, 49 KB) ----------------
#define L_X   0        // x rows 32..63: [32][512] f16 unpadded, unit-swizzled = 32768
#define L_H1  32768    // h1 [32][136] f16 = 8704 ; route_s overlays h1..p (64*68 f32)
#define L_H2  41472    // h2 [32][72]  f16 = 4608
#define L_P   46080    // p  [64][16]  f32 = 4096
#define L_TOT 50176

// ============ one prep kernel: convert x + fragment-pack all weights ============
__global__ __launch_bounds__(256) void prep_all(
    const float* __restrict__ x, const float* __restrict__ rW,
    const float* __restrict__ W1, const float* __restrict__ W2,
    const float* __restrict__ W3,
    f16* __restrict__ xh, f16* __restrict__ w1f, f16* __restrict__ w2f,
    f16* __restrict__ w3f, f16* __restrict__ rwf) {
  __shared__ float sb[8704];
  const int bid = blockIdx.x, t = threadIdx.x;
  if (bid < 512) {
    // ---- w1f: W1 [l][512k][128n] -> frag[(l*4+ng)*32+ks][lane][8] ----
    const int l = bid >> 3, kc = bid & 7;            // kc: 64-k chunk
    const float* src = W1 + ((size_t)l * 512 + kc * 64) * 128;
#pragma unroll
    for (int i = 0; i < 32; ++i) {
      int idx = t + i * 256;
      int k_l = idx >> 7, n = idx & 127;
      sb[n * 68 + k_l] = src[(size_t)k_l * 128 + n];
    }
    __syncthreads();
#pragma unroll
    for (int p = 0; p < 4; ++p) {
      int c = p * 4 + (t >> 6);                      // 16 combos (ng, ksl)
      int ng = c >> 2, ksl = c & 3;
      int lane = t & 63;
      int n = ng * 32 + (lane & 31);
      int k0 = ksl * 16 + (lane >> 5) * 8;
      f16x8 h;
#pragma unroll
      for (int j = 0; j < 8; ++j) h[j] = (f16)sb[n * 68 + k0 + j];
      *(f16x8*)(w1f + ((size_t)((l * 4 + ng) * 32 + kc * 4 + ksl) * 64 + lane) * 8) = h;
    }
  } else if (bid < 768) {
    // ---- xh: fp32 -> f16, row-major ----
    size_t base = (size_t)(bid - 512) * 16384;
#pragma unroll
    for (int i = 0; i < 8; ++i) {
      size_t idx = base + ((size_t)t + i * 256) * 8;
      float4 a = *(const float4*)(x + idx);
      float4 b = *(const float4*)(x + idx + 4);
      f16x8 h = {(f16)a.x,(f16)a.y,(f16)a.z,(f16)a.w,(f16)b.x,(f16)b.y,(f16)b.z,(f16)b.w};
      *(f16x8*)(xh + idx) = h;
    }
  } else if (bid < 832) {
    // ---- w2f + w3f, one leaf per block ----
    const int l = bid - 768;
    const float* src = W2 + (size_t)l * 128 * 64;
#pragma unroll
    for (int i = 0; i < 32; ++i) {
      int idx = t + i * 256;
      int k_l = idx >> 6, n = idx & 63;
      sb[n * 132 + k_l] = src[(size_t)k_l * 64 + n];
    }
    __syncthreads();
#pragma unroll
    for (int p = 0; p < 4; ++p) {
      int c = p * 4 + (t >> 6);                      // 16 combos (nb, ks)
      int nb = c >> 2, ks = c & 3;
      int lane = t & 63;
      int n = nb * 16 + (lane & 15);
      int k0 = ks * 32 + (lane >> 4) * 8;
      f16x8 h;
#pragma unroll
      for (int j = 0; j < 8; ++j) h[j] = (f16)sb[n * 132 + k0 + j];
      *(f16x8*)(w2f + ((size_t)((l * 4 + nb) * 4 + ks) * 64 + lane) * 8) = h;
    }
    if (t < 128) {                                   // w3f (n pad 8->16 zero)
      int ks = t >> 6, lane = t & 63;
      int n = lane & 15;
      int k0 = ks * 32 + (lane >> 4) * 8;
      f16x8 h;
#pragma unroll
      for (int j = 0; j < 8; ++j)
        h[j] = (n < 8) ? (f16)W3[((size_t)l * 64 + k0 + j) * 8 + n] : (f16)0.f;
      *(f16x8*)(w3f + ((size_t)(l * 2 + ks) * 64 + lane) * 8) = h;
    }
  } else {
    // ---- rwf: router W, mfma32 frags (node 63 zero) ----
    int c = (bid - 832) * 4 + (t >> 6);              // 0..63 = (ngr, ks)
    int ngr = c >> 5, ks = c & 31;
    int lane = t & 63;
    int n = ngr * 32 + (lane & 31);
    int k0 = ks * 16 + (lane >> 5) * 8;
    f16x8 h;
#pragma unroll
    for (int j = 0; j < 8; ++j)
      h[j] = (n < 63) ? (f16)rW[(size_t)n * 512 + k0 + j] : (f16)0.f;
    *(f16x8*)(rwf + ((size_t)c * 64 + lane) * 8) = h;
  }
}

// ============ fused: router + per-leaf MLP + weighted sum ============
// 256 threads (4 waves). Block: 64 batch rows (32 reg-A + 32 LDS-A) x 16 leaves.
__global__ __launch_bounds__(256, 2) void fused_tree(
    const f16* __restrict__ xh, const f16* __restrict__ w1f,
    const f16* __restrict__ w2f, const f16* __restrict__ w3f,
    const f16* __restrict__ rwf, const float* __restrict__ rb,
    const float* __restrict__ b1, const float* __restrict__ b2,
    const float* __restrict__ b3, float* __restrict__ out) {
  __shared__ char smem[L_TOT];
  f16*   x_lds   = (f16*)(smem + L_X);
  f16*   h1_lds  = (f16*)(smem + L_H1);
  float* route_s = (float*)(smem + L_H1);   // [64][68] f32, dead before h1 use
  f16*   h2_lds  = (f16*)(smem + L_H2);
  float* p_lds   = (float*)(smem + L_P);

  const int t = threadIdx.x;
  const int w = t >> 6, L = t & 63;
  const int l16 = L & 15, quad = L >> 4;
  const int r31 = L & 31, kp = L >> 5;

  // XCD-aware decode: 2 XCDs per leaf-group -> leaf W1 slice L2-resident
  const int bid = blockIdx.x;
  const int r8 = bid & 7;
  const int lg0 = (r8 >> 1) * 16;
  const int btp = (bid >> 3) * 2 + (r8 & 1);     // 0..127
  const int b0 = btp * 64;

  // ---- stage x rows b0+32..63 into swizzled LDS (1 row per wave-issue) ----
#pragma unroll
  for (int j = 0; j < 8; ++j) {
    int r = w * 8 + j;
    int u = (L & 56) | ((L & 7) ^ (r & 7));
    cp16(xh + (size_t)(b0 + 32 + r) * 512 + u * 8, smem + r * 1024);
  }
  // ---- A0: rows b0..b0+31 in registers, mfma32 A-layout ----
  f16x8 a0[32];
#pragma unroll
  for (int ks = 0; ks < 32; ++ks)
    a0[ks] = *(const f16x8*)(xh + (size_t)(b0 + r31) * 512 + ks * 16 + kp * 8);
  __syncthreads();

  // ---- router: waves 0,1 -> bt0 (reg A), waves 2,3 -> bt1 (LDS A) ----
  {
    const int btr = w >> 1, ngr = w & 1;
    f32x16 accr;
#pragma unroll
    for (int i = 0; i < 16; ++i) accr[i] = 0.f;
    const f16* rbase = rwf + (size_t)(ngr * 32) * 512 + (size_t)L * 8;
#pragma unroll
    for (int ks = 0; ks < 32; ++ks) {
      f16x8 B = *(const f16x8*)(rbase + (size_t)ks * 512);
      f16x8 A;
      if (btr == 0) A = a0[ks];
      else {
        int u = ks * 2 + kp;
        A = *(const f16x8*)(x_lds + r31 * 512 + ((u & 56) | ((u & 7) ^ (r31 & 7))) * 8);
      }
      accr = MFMA32(A, B, accr);
    }
    int node = ngr * 32 + r31;
    float rbv = (node < 63) ? rb[node] : 0.f;
#pragma unroll
    for (int reg = 0; reg < 16; ++reg) {
      int rr = btr * 32 + (reg & 3) + 8 * (reg >> 2) + 4 * kp;
      route_s[rr * 68 + node] = 1.f / (1.f + __expf(-(accr[reg] + rbv)));
    }
  }
  __syncthreads();
  // ---- path products (into regs, then store after sync: p overlays route_s) ----
  float prod[4];
  {
    int row = t >> 2, j0 = t & 3;
#pragma unroll
    for (int i = 0; i < 4; ++i) {
      int l = lg0 + j0 * 4 + i;
      float pr = 1.f;
#pragma unroll
      for (int lev = 0; lev < 6; ++lev) {
        int node = (1 << lev) - 1 + (l >> (6 - lev));
        float d = route_s[row * 68 + node];
        pr *= ((l >> (5 - lev)) & 1) ? (1.f - d) : d;
      }
      prod[i] = pr;
    }
  }
  __syncthreads();
  {
    int row = t >> 2, j0 = t & 3;
#pragma unroll
    for (int i = 0; i < 4; ++i) p_lds[row * 16 + j0 * 4 + i] = prod[i];
  }
  __syncthreads();

  // ---- main leaf loop ----
  const f16* w1base = w1f + ((size_t)(lg0 * 4 + w) * 32) * 512 + (size_t)L * 8;
  f16x8 bq[2][4];
#pragma unroll
  for (int s = 0; s < 4; ++s) bq[0][s] = *(const f16x8*)(w1base + (size_t)s * 512);

  f32x4 acc_out = {0.f, 0.f, 0.f, 0.f};
  const int mt = w >> 1, nt2 = w & 1;     // GEMM2 wave mapping

#pragma unroll 1
  for (int li = 0; li < 16; ++li) {
    const int l = lg0 + li;
    const size_t leafoff = (size_t)li * 65536;

    // ---- GEMM1: X(64x512) @ W1[l] -> H1(64x128); no barriers, B stream ----
    f32x16 acc1r, acc1l;
#pragma unroll
    for (int i = 0; i < 16; ++i) { acc1r[i] = 0.f; acc1l[i] = 0.f; }

#pragma unroll
    for (int q = 0; q < 8; ++q) {
      // R8 CHANGE: batch the 4 A1 LDS reads up front (independent), so the
      // lgkmcnt drain overlaps the 4 reg-only acc1r MFMAs below.
      f16x8 A1[4];
#pragma unroll
      for (int s = 0; s < 4; ++s) {
        int u = (q * 4 + s) * 2 + kp;
        A1[s] = *(const f16x8*)(x_lds + r31 * 512 + ((u & 56) | ((u & 7) ^ (r31 & 7))) * 8);
      }
      // global prefetch of next chunk (next leaf's q0 when q==7)
      size_t nxt = (q < 7) ? (leafoff + (size_t)(q + 1) * 2048)
                           : ((li < 15) ? (leafoff + 65536) : (leafoff + 7 * 2048));
#pragma unroll
      for (int s = 0; s < 4; ++s)
        bq[(q + 1) & 1][s] = *(const f16x8*)(w1base + nxt + (size_t)s * 512);
      // reg-only MFMAs first (no memory waits)
#pragma unroll
      for (int s = 0; s < 4; ++s)
        acc1r = MFMA32(a0[q * 4 + s], bq[q & 1][s], acc1r);
      // LDS-half MFMAs (A1 drained progressively behind acc1r issue)
#pragma unroll
      for (int s = 0; s < 4; ++s)
        acc1l = MFMA32(A1[s], bq[q & 1][s], acc1l);
    }

    // B2/B3 frag loads (coalesced; reused for both batch halves)
    f16x8 bw2[2][4];
#pragma unroll
    for (int n16 = 0; n16 < 2; ++n16)
#pragma unroll
      for (int ks = 0; ks < 4; ++ks)
        bw2[n16][ks] = *(const f16x8*)(w2f + ((size_t)((l * 4 + nt2 * 2 + n16) * 4 + ks) * 64 + L) * 8);
    f16x8 bw3[2];
#pragma unroll
    for (int ks = 0; ks < 2; ++ks)
      bw3[ks] = *(const f16x8*)(w3f + ((size_t)(l * 2 + ks) * 64 + L) * 8);

    const int n1 = w * 32 + r31;
    const float bias1 = b1[l * 128 + n1];

    // ---- h1 <- bt0 ----
#pragma unroll
    for (int reg = 0; reg < 16; ++reg) {
      int rr = (reg & 3) + 8 * (reg >> 2) + 4 * kp;
      float v = acc1r[reg] + bias1;
      h1_lds[rr * 136 + n1] = (f16)(v > 0.f ? v : 0.f);
    }
    __syncthreads();   // S1: h1(bt0) visible

#define GEMM2_BT(btv)                                                          \
    {                                                                          \
      f32x4 acc2[2] = {{0.f,0.f,0.f,0.f},{0.f,0.f,0.f,0.f}};                   \
      _Pragma("unroll")                                                        \
      for (int ks = 0; ks < 4; ++ks) {                                         \
        f16x8 A = *(const f16x8*)(h1_lds + (mt * 16 + l16) * 136 + ks * 32 + quad * 8); \
        _Pragma("unroll")                                                      \
        for (int n16 = 0; n16 < 2; ++n16) acc2[n16] = MFMA16(A, bw2[n16][ks], acc2[n16]); \
      }                                                                        \
      _Pragma("unroll")                                                        \
      for (int n16 = 0; n16 < 2; ++n16) {                                      \
        int n2 = nt2 * 32 + n16 * 16 + l16;                                    \
        float bias2 = b2[l * 64 + n2];                                         \
        _Pragma("unroll")                                                      \
        for (int rg = 0; rg < 4; ++rg) {                                       \
          int r2 = mt * 16 + quad * 4 + rg;                                    \
          float v = acc2[n16][rg] + bias2;                                     \
          v = v > 0.f ? v : 0.f;                                               \
          h2_lds[r2 * 72 + n2] = (f16)(v * p_lds[((btv) * 32 + r2) * 16 + li]); \
        }                                                                      \
      }                                                                        \
    }

    GEMM2_BT(0)
    __syncthreads();   // S2: h2(bt0) visible; h1 reads done

    if (w < 2) {       // GEMM3 bt0 (waves 0,1)
#pragma unroll
      for (int ks = 0; ks < 2; ++ks) {
        f16x8 A = *(const f16x8*)(h2_lds + ((w & 1) * 16 + l16) * 72 + ks * 32 + quad * 8);
        acc_out = MFMA16(A, bw3[ks], acc_out);
      }
    }
    // ---- h1 <- bt1 (disjoint from h2 reads above) ----
#pragma unroll
    for (int reg = 0; reg < 16; ++reg) {
      int rr = (reg & 3) + 8 * (reg >> 2) + 4 * kp;
      float v = acc1l[reg] + bias1;
      h1_lds[rr * 136 + n1] = (f16)(v > 0.f ? v : 0.f);
    }
    __syncthreads();   // S3: h1(bt1) visible; h2(bt0) reads done

    GEMM2_BT(1)
    __syncthreads();   // S4: h2(bt1) visible; h1 reads done

    if (w >= 2) {      // GEMM3 bt1 (waves 2,3)
#pragma unroll
      for (int ks = 0; ks < 2; ++ks) {
        f16x8 A = *(const f16x8*)(h2_lds + ((w & 1) * 16 + l16) * 72 + ks * 32 + quad * 8);
        acc_out = MFMA16(A, bw3[ks], acc_out);
      }
    }
#undef GEMM2_BT
  }

  // ---- final epilogue: + sum_li p*b3, atomicAdd ----
  if (l16 < 8) {
    const int btf = w >> 1, mtf = w & 1;
    float b3v[16];
#pragma unroll
    for (int li2 = 0; li2 < 16; ++li2) b3v[li2] = b3[(lg0 + li2) * 8 + l16];
#pragma unroll
    for (int rg = 0; rg < 4; ++rg) {
      int rloc = btf * 32 + mtf * 16 + quad * 4 + rg;
      float v = acc_out[rg];
#pragma unroll
      for (int li2 = 0; li2 < 16; ++li2) v += p_lds[rloc * 16 + li2] * b3v[li2];
      atomicAdd(out + (size_t)(b0 + rloc) * 8 + l16, v);
    }
  }
}

extern "C" void kernel_launch(void* const* d_in, const int* in_sizes, int n_in,
                              void* d_out, int out_size, void* d_ws, size_t ws_size,
                              hipStream_t stream) {
  const float* x  = (const float*)d_in[0];
  const float* rW = (const float*)d_in[1];
  const float* rb = (const float*)d_in[2];
  const float* W1 = (const float*)d_in[3];
  const float* b1 = (const float*)d_in[4];
  const float* W2 = (const float*)d_in[5];
  const float* b2 = (const float*)d_in[6];
  const float* W3 = (const float*)d_in[7];
  const float* b3 = (const float*)d_in[8];
  float* out = (float*)d_out;

  if (ws_size < WS_NEED) return;

  char* ws = (char*)d_ws;
  f16* xh  = (f16*)(ws + WS_XH);
  f16* w1f = (f16*)(ws + WS_W1F);
  f16* w2f = (f16*)(ws + WS_W2F);
  f16* w3f = (f16*)(ws + WS_W3F);
  f16* rwf = (f16*)(ws + WS_RWF);

  hipMemsetAsync(d_out, 0, (size_t)out_size * sizeof(float), stream);
  prep_all<<<848, 256, 0, stream>>>(x, rW, W1, W2, W3, xh, w1f, w2f, w3f, rwf);
  fused_tree<<<512, 256, 0, stream>>>(xh, w1f, w2f, w3f, rwf, rb, b1, b2, b3, out);
}